// Round 6
// baseline (34.211 us; speedup 1.0000x reference)
//
#include <hip/hip_runtime.h>

// Fused single-kernel GEMV chain for the DCE'd MHA (kv_len==1 => softmax==1):
//   v    = v_w  @ text + v_b              (2048 x 4096, 32 MB)
//   ctx  = wv   @ v    + bv               (2048 x 2048, 16 MB)  wv = in_w rows 4096..6143
//   attn = mo_w @ ctx  + mo_b             (2048 x 2048, 16 MB)
//   out  = visual + o_w @ attn + o_b      (4096 x 2048, 32 MB)
//
// R1-4: __threadfence = whole-L2 invalidate storm (230-250 us). R5 removed all
// cache maintenance (uncached system-scope for the ~8KB of cross-stage data)
// -> 32.9 us. Remaining gap vs 15.2 us floor: vmcnt drain coupling. vmcnt
// retires IN ORDER per wave, so any __syncthreads (vmcnt(0)) or wait-for-newest
// stalls on prefetch issued for LATER stages.
//
// R6: wave-role specialization so each wave's queue only ever holds what it
// needs next:
//   wave0: barrier manager + S2 compute (alone). Queue always clean ->
//          arrive-side vmcnt(0) free; loads x2 right after poll1 (whole wave
//          is past the release flag - lockstep), hiding LLC latency.
//   wave1: stages W2 (16 insts) THEN W3 (16) -> in-order retire means
//          "vmcnt(16)" == "W2 done, W3 still flying" before BAR3.
//   wave2: stages W4ab after x3 issue (x3 older -> counted dep-wait).
//   wave3: stages W4cd after the S3-reduce barrier (WAR on sB).
// All __syncthreads replaced by raw s_barrier + explicit per-wave s_waitcnt
// (+ sched_barrier(0) fences, guide rule 18). 7 barriers, all unconditional.
//
// Barrier tree: R4/R5 spread layout (leaf counters / root / fan-out release
// at 256B stride), system-scope relaxed atomics, zero cache maintenance.
// Residency: 1024 blocks = 256 CU x 4 (33 KB LDS), proven rounds 1-5.

#define ED 2048
#define VD 4096
#define NB 1024
#define NT 256
#define BAR_U 4224   // uints per barrier region (leafCnt@l*64, root@2048, rel@2112+l*64)

#define SCHED_FENCE() __builtin_amdgcn_sched_barrier(0)
#define BARRIER()     __builtin_amdgcn_s_barrier()

__device__ __forceinline__ float wave_red(float v) {
#pragma unroll
    for (int off = 32; off > 0; off >>= 1) v += __shfl_down(v, off, 64);
    return v;
}

__device__ __forceinline__ void gload_lds16(const float* g, float* l) {
    __builtin_amdgcn_global_load_lds(
        (const __attribute__((address_space(1))) void*)g,
        (__attribute__((address_space(3))) void*)l, 16, 0, 0);
}

// 16 KB row staged by ALL 4 waves (wave w -> chunks 4w..4w+3).
__device__ __forceinline__ void stage16k(const float* g, float* l, int wid, int lane) {
#pragma unroll
    for (int j = 0; j < 4; ++j) {
        const int c = wid * 4 + j;
        gload_lds16(g + c * 256 + lane * 4, l + c * 256);
    }
}
// 8 KB row staged by ONE wave (8 chunks, issued in order).
__device__ __forceinline__ void stage8k_1w(const float* g, float* l, int lane) {
#pragma unroll
    for (int c = 0; c < 8; ++c)
        gload_lds16(g + c * 256 + lane * 4, l + c * 256);
}

// Uncached (coherence-point) ops - no cache maintenance anywhere.
__device__ __forceinline__ void store_uc(float* p, float v) {
    union { float f; unsigned u; } c; c.f = v;
    __hip_atomic_store((unsigned*)p, c.u, __ATOMIC_RELAXED,
                       __HIP_MEMORY_SCOPE_SYSTEM);
}
__device__ __forceinline__ float2 load_uc2(const float* p) {
    union { unsigned long long u; float2 f; } c;
    c.u = __hip_atomic_load((const unsigned long long*)p, __ATOMIC_RELAXED,
                            __HIP_MEMORY_SCOPE_SYSTEM);
    return c.f;
}

// t0 only. Caller guarantees wave0's queue holds ONLY the x-stores.
__device__ __forceinline__ void arrive_tree(unsigned* base, int b) {
    asm volatile("s_waitcnt vmcnt(0)" ::: "memory");   // x-stores acked at LLC
    if (__hip_atomic_fetch_add(base + ((b >> 5) << 6), 1u,
            __ATOMIC_RELAXED, __HIP_MEMORY_SCOPE_SYSTEM) == 31u) {
        if (__hip_atomic_fetch_add(base + 2048, 1u,
                __ATOMIC_RELAXED, __HIP_MEMORY_SCOPE_SYSTEM) == 31u) {
#pragma unroll
            for (int l = 0; l < 32; ++l)
                __hip_atomic_store(base + 2112 + l * 64, 1u,
                                   __ATOMIC_RELAXED, __HIP_MEMORY_SCOPE_SYSTEM);
        }
    }
}
// t0 only (whole wave0 iterates the loop in lockstep -> after it, ALL of
// wave0 is past the release point).
__device__ __forceinline__ void poll_release(unsigned* base, int b) {
    unsigned* rel = base + 2112 + ((b >> 5) << 6);
    int spins = 0;
    while (__hip_atomic_load(rel, __ATOMIC_RELAXED,
                             __HIP_MEMORY_SCOPE_SYSTEM) == 0u) {
        __builtin_amdgcn_s_sleep(2);
        if (++spins > (1 << 17)) break;   // visible fail, never hang
    }
}

__global__ __launch_bounds__(NT, 4)
void fused_chain(const float* __restrict__ visual,
                 const float* __restrict__ text,
                 const float* __restrict__ v_w,  const float* __restrict__ v_b,
                 const float* __restrict__ wv,   const float* __restrict__ bv,
                 const float* __restrict__ mo_w, const float* __restrict__ mo_b,
                 const float* __restrict__ o_w,  const float* __restrict__ o_b,
                 float* __restrict__ vvec, float* __restrict__ ctx,
                 float* __restrict__ attn, unsigned* __restrict__ flags,
                 float* __restrict__ out)
{
    __shared__ __align__(16) float sA[4096];   // 16 KB slot A
    __shared__ __align__(16) float sB[4096];   // 16 KB slot B
    __shared__ float red[16];

    const int t    = threadIdx.x;
    const int b    = blockIdx.x;
    const int lane = t & 63;
    const int wid  = t >> 6;
    const int r2   = 2 * b;
    const int r4   = 4 * b;

    const float4* A4 = (const float4*)sA;
    const float4* B4 = (const float4*)sB;

    // ---- t0: all biases + residual up front (retired by pre-BAR1 drain) ----
    float bi10=0.f, bi11=0.f, bi20=0.f, bi21=0.f, bi30=0.f, bi31=0.f;
    float bo0=0.f, bo1=0.f, bo2=0.f, bo3=0.f;
    if (t == 0) {
        bi10 = v_b[r2];  bi11 = v_b[r2+1];
        bi20 = bv[r2];   bi21 = bv[r2+1];
        bi30 = mo_b[r2]; bi31 = mo_b[r2+1];
        bo0 = o_b[r4]   + visual[r4];
        bo1 = o_b[r4+1] + visual[r4+1];
        bo2 = o_b[r4+2] + visual[r4+2];
        bo3 = o_b[r4+3] + visual[r4+3];
    }

    // ---- S1 staging (all waves) + x1 ----
    stage16k(v_w + (size_t)r2 * VD,       sA, wid, lane);
    stage16k(v_w + (size_t)(r2 + 1) * VD, sB, wid, lane);
    const float4* x1p = (const float4*)text;
    float4 x1[4];
#pragma unroll
    for (int j = 0; j < 4; ++j) x1[j] = x1p[t + j * NT];

    asm volatile("s_waitcnt vmcnt(0)" ::: "memory");
    SCHED_FENCE();
    BARRIER();                                     // BAR1: S1 data ready
    SCHED_FENCE();

    // ---- stage 1: v = v_w @ text + v_b (all waves) ----
    float a0 = 0.f, a1 = 0.f;
#pragma unroll
    for (int j = 0; j < 4; ++j) {
        float4 wa = A4[t + j * NT], wb = B4[t + j * NT];
        a0 = fmaf(wa.x, x1[j].x, a0); a0 = fmaf(wa.y, x1[j].y, a0);
        a0 = fmaf(wa.z, x1[j].z, a0); a0 = fmaf(wa.w, x1[j].w, a0);
        a1 = fmaf(wb.x, x1[j].x, a1); a1 = fmaf(wb.y, x1[j].y, a1);
        a1 = fmaf(wb.z, x1[j].z, a1); a1 = fmaf(wb.w, x1[j].w, a1);
    }
    a0 = wave_red(a0); a1 = wave_red(a1);
    if (lane == 0) { red[wid] = a0; red[8 + wid] = a1; }
    asm volatile("s_waitcnt lgkmcnt(0)" ::: "memory");
    SCHED_FENCE();
    BARRIER();                                     // BAR2: red ready, S1 LDS reads done
    SCHED_FENCE();

    // wave1: stage W2 (s0,s1) THEN W3 (s2,s3). In-order retire => vmcnt(16) = W2 done.
    if (wid == 1) {
        stage8k_1w(wv + (size_t)r2 * ED,         sA,        lane);
        stage8k_1w(wv + (size_t)(r2 + 1) * ED,   sA + 2048, lane);
        stage8k_1w(mo_w + (size_t)r2 * ED,       sB,        lane);
        stage8k_1w(mo_w + (size_t)(r2 + 1) * ED, sB + 2048, lane);
    }
    if (t == 0) {
        store_uc(vvec + r2,     red[0] + red[1] + red[2] + red[3] + bi10);
        store_uc(vvec + r2 + 1, red[8] + red[9] + red[10] + red[11] + bi11);
        arrive_tree(flags, b);
        poll_release(flags, b);
    }

    // wave0 (all lanes, past release1): load x2 NOW - latency hides under W2 stream.
    float2 x2a[8], x2b[8];
    if (wid == 0) {
#pragma unroll
        for (int j = 0; j < 8; ++j) {
            const float* p = vvec + 4 * (lane + j * 64);
            x2a[j] = load_uc2(p); x2b[j] = load_uc2(p + 2);
        }
    }

    if (wid == 1) { asm volatile("s_waitcnt vmcnt(16)" ::: "memory"); }  // W2 done, W3 flying
    else          { asm volatile("s_waitcnt vmcnt(0)"  ::: "memory"); }
    SCHED_FENCE();
    BARRIER();                                     // BAR3: release1 + W2 in LDS
    SCHED_FENCE();

    // ---- stage 2: ctx = wv @ v + bv  (wave0 ALONE; others pass through) ----
    if (wid == 0) {
        float s20 = 0.f, s21 = 0.f;
#pragma unroll
        for (int j = 0; j < 8; ++j) {
            float4 wa = A4[lane + j * 64];          // row r2
            float4 wb = A4[512 + lane + j * 64];    // row r2+1
            s20 = fmaf(wa.x, x2a[j].x, s20); s20 = fmaf(wa.y, x2a[j].y, s20);
            s20 = fmaf(wa.z, x2b[j].x, s20); s20 = fmaf(wa.w, x2b[j].y, s20);
            s21 = fmaf(wb.x, x2a[j].x, s21); s21 = fmaf(wb.y, x2a[j].y, s21);
            s21 = fmaf(wb.z, x2b[j].x, s21); s21 = fmaf(wb.w, x2b[j].y, s21);
        }
        s20 = wave_red(s20); s21 = wave_red(s21);
        if (t == 0) {
            store_uc(ctx + r2,     s20 + bi20);
            store_uc(ctx + r2 + 1, s21 + bi21);
            arrive_tree(flags + BAR_U, b);
            poll_release(flags + BAR_U, b);
        }
    }

    asm volatile("s_waitcnt vmcnt(0)" ::: "memory");  // wave1 drains W3 (needed for S3)
    SCHED_FENCE();
    BARRIER();                                     // BAR4: release2 + W3 in LDS + S2 reads done
    SCHED_FENCE();

    // ---- stage 3: attn = mo_w @ ctx + mo_b (all waves) ----
    float2 xl[2], xh[2];
#pragma unroll
    for (int j = 0; j < 2; ++j) {                  // x3 FIRST (older than W4ab)
        const float* p = ctx + 4 * (t + j * NT);
        xl[j] = load_uc2(p); xh[j] = load_uc2(p + 2);
    }
    SCHED_FENCE();
    if (wid == 2) {                                // W4 rows r4,r4+1 -> sA (free after S2)
        stage8k_1w(o_w + (size_t)r4 * ED,       sA,        lane);
        stage8k_1w(o_w + (size_t)(r4 + 1) * ED, sA + 2048, lane);
    }
    a0 = 0.f; a1 = 0.f;
#pragma unroll
    for (int j = 0; j < 2; ++j) {
        float4 wa = B4[t + j * NT], wb = B4[512 + t + j * NT];
        a0 = fmaf(wa.x, xl[j].x, a0); a0 = fmaf(wa.y, xl[j].y, a0);
        a0 = fmaf(wa.z, xh[j].x, a0); a0 = fmaf(wa.w, xh[j].y, a0);
        a1 = fmaf(wb.x, xl[j].x, a1); a1 = fmaf(wb.y, xl[j].y, a1);
        a1 = fmaf(wb.z, xh[j].x, a1); a1 = fmaf(wb.w, xh[j].y, a1);
    }
    a0 = wave_red(a0); a1 = wave_red(a1);
    if (lane == 0) { red[wid] = a0; red[8 + wid] = a1; }
    asm volatile("s_waitcnt lgkmcnt(0)" ::: "memory");
    SCHED_FENCE();
    BARRIER();                                     // BAR5: red ready, S3 LDS reads done
    SCHED_FENCE();

    if (t == 0) {
        store_uc(attn + r2,     red[0] + red[1] + red[2] + red[3] + bi30);
        store_uc(attn + r2 + 1, red[8] + red[9] + red[10] + red[11] + bi31);
        arrive_tree(flags + 2 * BAR_U, b);
    }
    if (wid == 3) {                                // W4 rows r4+2,r4+3 -> sB (free after S3)
        stage8k_1w(o_w + (size_t)(r4 + 2) * ED, sB,        lane);
        stage8k_1w(o_w + (size_t)(r4 + 3) * ED, sB + 2048, lane);
    }
    if (t == 0) poll_release(flags + 2 * BAR_U, b);

    asm volatile("s_waitcnt vmcnt(0)" ::: "memory");  // wave2: W4ab; wave3: W4cd
    SCHED_FENCE();
    BARRIER();                                     // BAR6: release3 + all W4 in LDS
    SCHED_FENCE();

    // ---- stage 4: out = visual + o_w @ attn + o_b (all waves, 4 rows) ----
#pragma unroll
    for (int j = 0; j < 2; ++j) {
        const float* p = attn + 4 * (t + j * NT);
        xl[j] = load_uc2(p); xh[j] = load_uc2(p + 2);
    }
    float c0 = 0.f, c1 = 0.f, c2 = 0.f, c3 = 0.f;
#pragma unroll
    for (int j = 0; j < 2; ++j) {
        float4 wa = A4[t + j * NT], wb = A4[512 + t + j * NT];
        float4 wc = B4[t + j * NT], wd = B4[512 + t + j * NT];
        c0 = fmaf(wa.x, xl[j].x, c0); c0 = fmaf(wa.y, xl[j].y, c0);
        c0 = fmaf(wa.z, xh[j].x, c0); c0 = fmaf(wa.w, xh[j].y, c0);
        c1 = fmaf(wb.x, xl[j].x, c1); c1 = fmaf(wb.y, xl[j].y, c1);
        c1 = fmaf(wb.z, xh[j].x, c1); c1 = fmaf(wb.w, xh[j].y, c1);
        c2 = fmaf(wc.x, xl[j].x, c2); c2 = fmaf(wc.y, xl[j].y, c2);
        c2 = fmaf(wc.z, xh[j].x, c2); c2 = fmaf(wc.w, xh[j].y, c2);
        c3 = fmaf(wd.x, xl[j].x, c3); c3 = fmaf(wd.y, xl[j].y, c3);
        c3 = fmaf(wd.z, xh[j].x, c3); c3 = fmaf(wd.w, xh[j].y, c3);
    }
    c0 = wave_red(c0); c1 = wave_red(c1); c2 = wave_red(c2); c3 = wave_red(c3);
    if (lane == 0) {
        red[wid] = c0; red[4 + wid] = c1; red[8 + wid] = c2; red[12 + wid] = c3;
    }
    asm volatile("s_waitcnt lgkmcnt(0)" ::: "memory");
    SCHED_FENCE();
    BARRIER();                                     // BAR7
    SCHED_FENCE();
    if (t == 0) {
        out[r4]     = red[0]  + red[1]  + red[2]  + red[3]  + bo0;
        out[r4 + 1] = red[4]  + red[5]  + red[6]  + red[7]  + bo1;
        out[r4 + 2] = red[8]  + red[9]  + red[10] + red[11] + bo2;
        out[r4 + 3] = red[12] + red[13] + red[14] + red[15] + bo3;
    }
}

extern "C" void kernel_launch(void* const* d_in, const int* in_sizes, int n_in,
                              void* d_out, int out_size, void* d_ws, size_t ws_size,
                              hipStream_t stream) {
    (void)in_sizes; (void)n_in; (void)out_size; (void)ws_size;
    const float* visual = (const float*)d_in[0];   // [4096]
    const float* text   = (const float*)d_in[1];   // [4096]
    // d_in[2..5] = q_w, q_b, k_w, k_b -> dead (softmax over single key == 1)
    const float* v_w  = (const float*)d_in[6];     // [2048, 4096]
    const float* v_b  = (const float*)d_in[7];     // [2048]
    const float* in_w = (const float*)d_in[8];     // [6144, 2048]
    const float* in_b = (const float*)d_in[9];     // [6144]
    const float* mo_w = (const float*)d_in[10];    // [2048, 2048]
    const float* mo_b = (const float*)d_in[11];    // [2048]
    const float* o_w  = (const float*)d_in[12];    // [4096, 2048]
    const float* o_b  = (const float*)d_in[13];    // [4096]
    float* out = (float*)d_out;                    // [4096]

    const float* wv = in_w + (size_t)2 * ED * ED;  // in_w rows 4096..6143
    const float* bv = in_b + 2 * ED;

    float* ws   = (float*)d_ws;
    float* vvec = ws;               // [2048]
    float* ctx  = ws + ED;          // [2048]
    float* attn = ws + 2 * ED;      // [2048]
    unsigned* flags = (unsigned*)(ws + 8192);   // 3 x BAR_U uints @ 32 KB offset

    // Workspace is poisoned between iterations -> barrier state must be zeroed.
    hipMemsetAsync(flags, 0, 3 * BAR_U * sizeof(unsigned), stream);
    fused_chain<<<NB, NT, 0, stream>>>(visual, text, v_w, v_b, wv, bv,
                                       mo_w, mo_b, o_w, o_b,
                                       vvec, ctx, attn, flags, out);
}